// Round 8
// baseline (213.375 us; speedup 1.0000x reference)
//
#include <hip/hip_runtime.h>
#include <hip/hip_bf16.h>

typedef unsigned short u16;

#define B_    4
#define T_    4096
#define C_    512
#define H_    8
#define D_    64
#define WIN_  15
#define PAD_  7
#define M_    (B_*T_)      // 16384 rows
#define NQKV  1536
#define KDIM  512

typedef __bf16 bf16x8 __attribute__((ext_vector_type(8)));
typedef float  f32x4  __attribute__((ext_vector_type(4)));

__device__ __forceinline__ u16 f2bf(float f) {
    union { float f; unsigned int i; } c; c.f = f;
    unsigned int lsb = (c.i >> 16) & 1u;
    c.i += 0x7fffu + lsb;                 // round-to-nearest-even
    return (u16)(c.i >> 16);
}
__device__ __forceinline__ float bf2f(u16 u) {
    union { unsigned int i; float f; } c; c.i = ((unsigned int)u) << 16; return c.f;
}
__device__ __forceinline__ uint4 cvt8(const float4 a, const float4 b, float m) {
    union { uint4 u; u16 s[8]; } o;
    o.s[0] = f2bf(a.x * m); o.s[1] = f2bf(a.y * m);
    o.s[2] = f2bf(a.z * m); o.s[3] = f2bf(a.w * m);
    o.s[4] = f2bf(b.x * m); o.s[5] = f2bf(b.y * m);
    o.s[6] = f2bf(b.z * m); o.s[7] = f2bf(b.w * m);
    return o.u;
}

// Swizzled LDS chunk offset (u16 units). Chunk = 16B = 8 bf16.
// slot = sub ^ ((row>>1)&3) makes both staging writes and fragment reads
// conflict-free: 16B-class = (row&1)*4 + sub^((row>>1)&3) covers all 8
// classes in every consecutive 8-lane group.
__device__ __forceinline__ int swz(int row, int sub) {
    return (row * 4 + (sub ^ ((row >> 1) & 3))) * 8;
}

// ---------------------------------------------------------------------------
// Pack fp32 weights -> bf16 transposed Wt[n][k].
// Wt_qkv rows: [0,512)=Wq cols, [512,1024)=Wkv k-part, [1024,1536)=Wkv v-part.
// ---------------------------------------------------------------------------
__global__ void pack_weights(const float* __restrict__ Wq, const float* __restrict__ Wkv,
                             const float* __restrict__ Wp,
                             u16* __restrict__ Wt_qkv, u16* __restrict__ Wpt)
{
    int idx = blockIdx.x * blockDim.x + threadIdx.x;   // 0 .. 1536*512-1
    int n = idx >> 9;
    int k = idx & 511;
    float w = (n < 512) ? Wq[k * 512 + n] : Wkv[k * 1024 + (n - 512)];
    Wt_qkv[idx] = f2bf(w);
    if (idx < 512 * 512) Wpt[idx] = f2bf(Wp[k * 512 + n]);
}

// ---------------------------------------------------------------------------
// 128x128 tile MFMA GEMM, C = A(MxK) * Bt(NxK)^T + bias.
// A_FP32_MASK: A fp32 (stride lda floats), scaled by amask[row] + cvt bf16
//   during staging. Else A bf16 stride lda.
// USE_MASK: epilogue multiplies by amask[row] (fp32).
// OUT_F32:  C written fp32, else bf16.
// Swizzled LDS (conflict-free) + LDS-transposed vectorized epilogue.
// ---------------------------------------------------------------------------
template<bool A_FP32_MASK, bool USE_MASK, bool OUT_F32>
__global__ __launch_bounds__(256) void gemm_bt_128(
    const void* __restrict__ Av, int lda,
    const float* __restrict__ amask,  // M fp32
    const u16* __restrict__ Bt,       // N x K row-major bf16 (pre-transposed)
    const float* __restrict__ bias0, const float* __restrict__ bias1,
    void* __restrict__ Cc,            // M x N row-major
    int K, int N)
{
    __shared__ __align__(16) char smem[16384];
    u16*   As = (u16*)smem;            // 128x32 bf16 (8 KB), swizzled
    u16*   Bs = (u16*)(smem + 8192);   // 128x32 bf16 (8 KB), swizzled
    float* Ct = (float*)smem;          // epilogue: 32x128 f32 (16 KB)

    const int tid  = threadIdx.x;
    const int wave = tid >> 6;
    const int lane = tid & 63;
    const int row0 = blockIdx.x * 128;
    const int col0 = blockIdx.y * 128;
    const int wm = (wave >> 1) * 64;   // wave's row offset in tile
    const int wn = (wave & 1) * 64;    // wave's col offset in tile

    f32x4 acc[4][4] = {};

    // chunk c in [0,512): tile row = c>>2, k-subcol = c&3
    const int c0 = tid;
    const int c1 = tid + 256;
    const int r0l = c0 >> 2, s0 = c0 & 3, r0g = row0 + r0l;
    const int r1l = c1 >> 2, s1 = c1 & 3, r1g = row0 + r1l;

    float m0 = 1.f, m1 = 1.f;
    if (A_FP32_MASK) { m0 = amask[r0g]; m1 = amask[r1g]; }

    const u16* Bb = Bt + (size_t)col0 * K;
    const int quad = lane >> 4;
    const int l16  = lane & 15;

    for (int k0 = 0; k0 < K; k0 += 32) {
        uint4 ra0, ra1;
        if (A_FP32_MASK) {
            const float* A0 = (const float*)Av + (size_t)r0g * lda + k0 + s0 * 8;
            const float* A1 = (const float*)Av + (size_t)r1g * lda + k0 + s1 * 8;
            ra0 = cvt8(*(const float4*)A0, *(const float4*)(A0 + 4), m0);
            ra1 = cvt8(*(const float4*)A1, *(const float4*)(A1 + 4), m1);
        } else {
            ra0 = *(const uint4*)((const u16*)Av + (size_t)r0g * lda + k0 + s0 * 8);
            ra1 = *(const uint4*)((const u16*)Av + (size_t)r1g * lda + k0 + s1 * 8);
        }
        uint4 rb0 = *(const uint4*)(Bb + (size_t)r0l * K + k0 + s0 * 8);
        uint4 rb1 = *(const uint4*)(Bb + (size_t)r1l * K + k0 + s1 * 8);

        __syncthreads();   // all waves done reading LDS from previous iter
        *(uint4*)&As[swz(r0l, s0)] = ra0;
        *(uint4*)&As[swz(r1l, s1)] = ra1;
        *(uint4*)&Bs[swz(r0l, s0)] = rb0;
        *(uint4*)&Bs[swz(r1l, s1)] = rb1;
        __syncthreads();   // staging visible to all waves

        bf16x8 a[4], b[4];
        #pragma unroll
        for (int i = 0; i < 4; i++) {
            a[i] = *(const bf16x8*)&As[swz(wm + i * 16 + l16, quad)];
            b[i] = *(const bf16x8*)&Bs[swz(wn + i * 16 + l16, quad)];
        }
        #pragma unroll
        for (int mi = 0; mi < 4; mi++)
            #pragma unroll
            for (int ni = 0; ni < 4; ni++)
                acc[mi][ni] = __builtin_amdgcn_mfma_f32_16x16x32_bf16(
                    a[mi], b[ni], acc[mi][ni], 0, 0, 0);
    }

    // ---- epilogue: 4 passes of 32 rows through LDS, vectorized stores ----
    // C/D frag layout: col=lane&15, row=quad*4+reg  [m89-verified]
    __syncthreads();                      // K-loop LDS reads done
    const int half = wm >> 6;             // which 64-row half this wave owns
    #pragma unroll
    for (int p = 0; p < 4; p++) {
        if ((p >> 1) == half) {
            const int mibase = (p & 1) * 2;
            #pragma unroll
            for (int mm = 0; mm < 2; mm++) {
                const int mi = mibase + mm;
                #pragma unroll
                for (int ni = 0; ni < 4; ni++) {
                    int col = wn + ni * 16 + l16;           // tile-local
                    int gcol = col0 + col;
                    float bval = (gcol < 512) ? bias0[gcol] : bias1[gcol - 512];
                    #pragma unroll
                    for (int r = 0; r < 4; r++) {
                        int rl = mm * 16 + quad * 4 + r;     // pass-local row
                        float v = acc[mi][ni][r] + bval;
                        if (USE_MASK) v *= amask[row0 + p * 32 + rl];
                        Ct[rl * 128 + col] = v;
                    }
                }
            }
        }
        __syncthreads();
        if (OUT_F32) {
            #pragma unroll
            for (int q = 0; q < 4; q++) {
                int u = q * 256 + tid;          // [0,1024): rl=u>>5, c4=u&31
                int rl = u >> 5, c4 = u & 31;
                float4 val = *(const float4*)&Ct[rl * 128 + c4 * 4];
                *(float4*)((float*)Cc + (size_t)(row0 + p * 32 + rl) * N + col0 + c4 * 4) = val;
            }
        } else {
            #pragma unroll
            for (int q = 0; q < 2; q++) {
                int u = q * 256 + tid;          // [0,512): rl=u>>4, c8=u&15
                int rl = u >> 4, c8 = u & 15;
                const float* src = &Ct[rl * 128 + c8 * 8];
                union { uint4 u4; u16 s[8]; } o;
                #pragma unroll
                for (int e = 0; e < 8; e++) o.s[e] = f2bf(src[e]);
                *(uint4*)((u16*)Cc + (size_t)(row0 + p * 32 + rl) * N + col0 + c8 * 8) = o.u4;
            }
        }
        __syncthreads();   // before next pass overwrites Ct
    }
}

// ---------------------------------------------------------------------------
// Windowed attention: thread-per-(t,h), k/v staged in LDS [jchunk][row].
// Rows outside [0,T) get the bias row. Output in place over the q slot.
// ---------------------------------------------------------------------------
__global__ __launch_bounds__(256) void attn_win2(u16* __restrict__ qkv,
                                                 const float* __restrict__ bkv)
{
    __shared__ uint4 klds[8 * 270];   // [j][row], row = t0-7+row
    __shared__ uint4 vlds[8 * 270];

    const int tid = threadIdx.x;
    const int bid = blockIdx.x;
    const int h  = bid & 7;
    const int b  = (bid >> 3) & 3;
    const int tb = bid >> 5;          // [0,16)
    const int t0 = tb * 256;

    #pragma unroll
    for (int i = 0; i < 9; i++) {
        int idx = i * 256 + tid;
        if (idx < 2160) {
            int row = idx % 270;
            int j   = idx / 270;
            int tt  = t0 - 7 + row;
            uint4 kc, vc;
            if ((unsigned)tt < (unsigned)T_) {
                const u16* g = qkv + ((size_t)b * T_ + tt) * NQKV + 512 + h * 64 + j * 8;
                kc = *(const uint4*)g;
                vc = *(const uint4*)(g + 512);
            } else {
                union { uint4 u; u16 s[8]; } pk, pv;
                #pragma unroll
                for (int e = 0; e < 8; e++) {
                    pk.s[e] = f2bf(bkv[h * 64 + j * 8 + e]);
                    pv.s[e] = f2bf(bkv[512 + h * 64 + j * 8 + e]);
                }
                kc = pk.u; vc = pv.u;
            }
            klds[j * 270 + row] = kc;
            vlds[j * 270 + row] = vc;
        }
    }
    __syncthreads();

    const size_t m = (size_t)b * T_ + t0 + tid;
    u16* qrow = qkv + m * NQKV + h * 64;

    float qf[64];
    #pragma unroll
    for (int j = 0; j < 8; j++) {
        union { uint4 u; u16 s[8]; } t;
        t.u = *(const uint4*)(qrow + j * 8);
        #pragma unroll
        for (int e = 0; e < 8; e++) qf[j * 8 + e] = bf2f(t.s[e]);
    }

    const float scale = 0.042313283f;   // ln(15)/64
    float s[WIN_];
    #pragma unroll
    for (int w = 0; w < WIN_; w++) {
        float acc = 0.f;
        #pragma unroll
        for (int j = 0; j < 8; j++) {
            union { uint4 u; u16 e[8]; } kc;
            kc.u = klds[j * 270 + tid + w];
            #pragma unroll
            for (int e2 = 0; e2 < 8; e2++)
                acc += qf[j * 8 + e2] * bf2f(kc.e[e2]);
        }
        s[w] = acc * scale;
    }

    float mx = s[0];
    #pragma unroll
    for (int w = 1; w < WIN_; w++) mx = fmaxf(mx, s[w]);
    float sum = 0.f;
    #pragma unroll
    for (int w = 0; w < WIN_; w++) { s[w] = __expf(s[w] - mx); sum += s[w]; }
    const float inv = 1.0f / sum;
    #pragma unroll
    for (int w = 0; w < WIN_; w++) s[w] *= inv;

    #pragma unroll
    for (int j = 0; j < 8; j++) {
        float o[8] = {};
        #pragma unroll
        for (int w = 0; w < WIN_; w++) {
            union { uint4 u; u16 e[8]; } vc;
            vc.u = vlds[j * 270 + tid + w];
            #pragma unroll
            for (int e2 = 0; e2 < 8; e2++) o[e2] += s[w] * bf2f(vc.e[e2]);
        }
        union { uint4 u; u16 e[8]; } oc;
        #pragma unroll
        for (int e2 = 0; e2 < 8; e2++) oc.e[e2] = f2bf(o[e2]);
        *(uint4*)(qrow + j * 8) = oc.u;
    }
}

// ---------------------------------------------------------------------------
// Workspace: 50 MiB total.
//   [0, 1.5Mi)    Wt_qkv (1536x512 bf16)
//   [1.5Mi, 2Mi)  Wpt    (512x512 bf16)
//   [2Mi, 50Mi)   qkv    (16384x1536 bf16); q section reused for attn output
// ---------------------------------------------------------------------------
extern "C" void kernel_launch(void* const* d_in, const int* in_sizes, int n_in,
                              void* d_out, int out_size, void* d_ws, size_t ws_size,
                              hipStream_t stream)
{
    const float* x    = (const float*)d_in[0];
    const float* mask = (const float*)d_in[1];
    const float* Wq   = (const float*)d_in[2];
    const float* bq   = (const float*)d_in[3];
    const float* Wkv  = (const float*)d_in[4];
    const float* bkv  = (const float*)d_in[5];
    const float* Wp   = (const float*)d_in[6];
    const float* bp   = (const float*)d_in[7];
    float* out = (float*)d_out;

    char* ws = (char*)d_ws;
    u16* Wt_qkv = (u16*)(ws);
    u16* Wpt    = (u16*)(ws + (size_t)(1536 * 1024));
    u16* qkv    = (u16*)(ws + (size_t)(2048 * 1024));

    pack_weights<<<NQKV * KDIM / 256, 256, 0, stream>>>(Wq, Wkv, Wp, Wt_qkv, Wpt);

    dim3 g1(M_ / 128, NQKV / 128);
    gemm_bt_128<true, false, false><<<g1, 256, 0, stream>>>(
        x, KDIM, mask, Wt_qkv, bq, bkv, qkv, KDIM, NQKV);

    attn_win2<<<(T_ / 256) * B_ * H_, 256, 0, stream>>>(qkv, bkv);

    dim3 g2(M_ / 128, C_ / 128);
    gemm_bt_128<false, true, true><<<g2, 256, 0, stream>>>(
        qkv, NQKV, mask, Wpt, bp, nullptr, out, KDIM, C_);
}

// Round 9
// 202.342 us; speedup vs baseline: 1.0545x; 1.0545x over previous
//
#include <hip/hip_runtime.h>
#include <hip/hip_bf16.h>

typedef unsigned short u16;

#define B_    4
#define T_    4096
#define C_    512
#define H_    8
#define D_    64
#define WIN_  15
#define PAD_  7
#define M_    (B_*T_)      // 16384 rows
#define NQKV  1536
#define KDIM  512

typedef __bf16 bf16x8 __attribute__((ext_vector_type(8)));
typedef float  f32x4  __attribute__((ext_vector_type(4)));

__device__ __forceinline__ u16 f2bf(float f) {
    union { float f; unsigned int i; } c; c.f = f;
    unsigned int lsb = (c.i >> 16) & 1u;
    c.i += 0x7fffu + lsb;                 // round-to-nearest-even
    return (u16)(c.i >> 16);
}
__device__ __forceinline__ float bf2f(u16 u) {
    union { unsigned int i; float f; } c; c.i = ((unsigned int)u) << 16; return c.f;
}
__device__ __forceinline__ uint4 cvt8(const float4 a, const float4 b, float m) {
    union { uint4 u; u16 s[8]; } o;
    o.s[0] = f2bf(a.x * m); o.s[1] = f2bf(a.y * m);
    o.s[2] = f2bf(a.z * m); o.s[3] = f2bf(a.w * m);
    o.s[4] = f2bf(b.x * m); o.s[5] = f2bf(b.y * m);
    o.s[6] = f2bf(b.z * m); o.s[7] = f2bf(b.w * m);
    return o.u;
}

// Swizzled LDS chunk offset (u16 units). Chunk = 16B = 8 bf16.
// slot = sub ^ ((row>>1)&3): 16B-class = (row&1)*4 + sub^((row>>1)&3)
// covers all 8 classes in every consecutive 8-lane group -> conflict-free
// for both staging writes and fragment reads. [R8: conflicts 3.1M -> 1.2M,
// residual was the (now removed) epilogue LDS traffic]
__device__ __forceinline__ int swz(int row, int sub) {
    return (row * 4 + (sub ^ ((row >> 1) & 3))) * 8;
}

// ---------------------------------------------------------------------------
// Pack fp32 weights -> bf16 transposed Wt[n][k].
// Wt_qkv rows: [0,512)=Wq cols, [512,1024)=Wkv k-part, [1024,1536)=Wkv v-part.
// ---------------------------------------------------------------------------
__global__ void pack_weights(const float* __restrict__ Wq, const float* __restrict__ Wkv,
                             const float* __restrict__ Wp,
                             u16* __restrict__ Wt_qkv, u16* __restrict__ Wpt)
{
    int idx = blockIdx.x * blockDim.x + threadIdx.x;   // 0 .. 1536*512-1
    int n = idx >> 9;
    int k = idx & 511;
    float w = (n < 512) ? Wq[k * 512 + n] : Wkv[k * 1024 + (n - 512)];
    Wt_qkv[idx] = f2bf(w);
    if (idx < 512 * 512) Wpt[idx] = f2bf(Wp[k * 512 + n]);
}

// ---------------------------------------------------------------------------
// 128x128 tile MFMA GEMM, C = A(MxK) * Bt(NxK)^T + bias.
// A_FP32_MASK: A fp32 (stride lda floats), scaled by amask[row] + cvt bf16
//   during staging. Else A bf16 stride lda.
// USE_MASK: epilogue multiplies by amask[row] (fp32).
// OUT_F32:  C written fp32, else bf16.
// MFMA called as mfma(b, a, acc): first operand supplies quad*4+reg index
// (-> C columns), second supplies lane&15 (-> C rows). Each lane then owns
// 4 CONSECUTIVE columns of one row -> register-direct vectorized stores,
// no epilogue LDS, no extra barriers (R8's transpose epilogue regressed).
// ---------------------------------------------------------------------------
template<bool A_FP32_MASK, bool USE_MASK, bool OUT_F32>
__global__ __launch_bounds__(256) void gemm_bt_128(
    const void* __restrict__ Av, int lda,
    const float* __restrict__ amask,  // M fp32
    const u16* __restrict__ Bt,       // N x K row-major bf16 (pre-transposed)
    const float* __restrict__ bias0, const float* __restrict__ bias1,
    void* __restrict__ Cc,            // M x N row-major
    int K, int N)
{
    __shared__ __align__(16) u16 As[128 * 32];
    __shared__ __align__(16) u16 Bs[128 * 32];

    const int tid  = threadIdx.x;
    const int wave = tid >> 6;
    const int lane = tid & 63;
    const int row0 = blockIdx.x * 128;
    const int col0 = blockIdx.y * 128;
    const int wm = (wave >> 1) * 64;   // wave's row offset in tile
    const int wn = (wave & 1) * 64;    // wave's col offset in tile

    f32x4 acc[4][4] = {};              // [ci][ri]

    // chunk c in [0,512): tile row = c>>2, k-subcol = c&3
    const int c0 = tid;
    const int c1 = tid + 256;
    const int r0l = c0 >> 2, s0 = c0 & 3, r0g = row0 + r0l;
    const int r1l = c1 >> 2, s1 = c1 & 3, r1g = row0 + r1l;

    float m0 = 1.f, m1 = 1.f;
    if (A_FP32_MASK) { m0 = amask[r0g]; m1 = amask[r1g]; }

    const u16* Bb = Bt + (size_t)col0 * K;
    const int quad = lane >> 4;
    const int l16  = lane & 15;

    for (int k0 = 0; k0 < K; k0 += 32) {
        uint4 ra0, ra1;
        if (A_FP32_MASK) {
            const float* A0 = (const float*)Av + (size_t)r0g * lda + k0 + s0 * 8;
            const float* A1 = (const float*)Av + (size_t)r1g * lda + k0 + s1 * 8;
            ra0 = cvt8(*(const float4*)A0, *(const float4*)(A0 + 4), m0);
            ra1 = cvt8(*(const float4*)A1, *(const float4*)(A1 + 4), m1);
        } else {
            ra0 = *(const uint4*)((const u16*)Av + (size_t)r0g * lda + k0 + s0 * 8);
            ra1 = *(const uint4*)((const u16*)Av + (size_t)r1g * lda + k0 + s1 * 8);
        }
        uint4 rb0 = *(const uint4*)(Bb + (size_t)r0l * K + k0 + s0 * 8);
        uint4 rb1 = *(const uint4*)(Bb + (size_t)r1l * K + k0 + s1 * 8);

        __syncthreads();   // all waves done reading LDS from previous iter
        *(uint4*)&As[swz(r0l, s0)] = ra0;
        *(uint4*)&As[swz(r1l, s1)] = ra1;
        *(uint4*)&Bs[swz(r0l, s0)] = rb0;
        *(uint4*)&Bs[swz(r1l, s1)] = rb1;
        __syncthreads();   // staging visible to all waves

        bf16x8 a[4], b[4];
        #pragma unroll
        for (int i = 0; i < 4; i++) {
            a[i] = *(const bf16x8*)&As[swz(wm + i * 16 + l16, quad)];
            b[i] = *(const bf16x8*)&Bs[swz(wn + i * 16 + l16, quad)];
        }
        #pragma unroll
        for (int ci = 0; ci < 4; ci++)
            #pragma unroll
            for (int ri = 0; ri < 4; ri++)
                acc[ci][ri] = __builtin_amdgcn_mfma_f32_16x16x32_bf16(
                    b[ci], a[ri], acc[ci][ri], 0, 0, 0);
    }

    // ---- epilogue: register-direct vectorized stores ----
    // D of mfma(b,a): lane&15 -> C row (within a[ri]), quad*4+reg -> C col
    // (within b[ci]); each lane: 4 consecutive cols of one row.
    #pragma unroll
    for (int ri = 0; ri < 4; ri++) {
        const int row = row0 + wm + ri * 16 + l16;
        float mval = 1.f;
        if (USE_MASK) mval = amask[row];
        #pragma unroll
        for (int ci = 0; ci < 4; ci++) {
            const int colb = col0 + wn + ci * 16 + quad * 4;
            float4 bv = (colb < 512) ? *(const float4*)(bias0 + colb)
                                     : *(const float4*)(bias1 + colb - 512);
            f32x4 v = acc[ci][ri];
            float v0 = v[0] + bv.x, v1 = v[1] + bv.y,
                  v2 = v[2] + bv.z, v3 = v[3] + bv.w;
            if (USE_MASK) { v0 *= mval; v1 *= mval; v2 *= mval; v3 *= mval; }
            if (OUT_F32) {
                float4 o = make_float4(v0, v1, v2, v3);
                *(float4*)((float*)Cc + (size_t)row * N + colb) = o;
            } else {
                union { uint2 u; u16 s[4]; } o;
                o.s[0] = f2bf(v0); o.s[1] = f2bf(v1);
                o.s[2] = f2bf(v2); o.s[3] = f2bf(v3);
                *(uint2*)((u16*)Cc + (size_t)row * N + colb) = o.u;
            }
        }
    }
}

// ---------------------------------------------------------------------------
// Windowed attention: thread-per-(t,h), k/v staged in LDS [jchunk][row].
// Rows outside [0,T) get the bias row. Output in place over the q slot.
// ---------------------------------------------------------------------------
__global__ __launch_bounds__(256) void attn_win2(u16* __restrict__ qkv,
                                                 const float* __restrict__ bkv)
{
    __shared__ uint4 klds[8 * 270];   // [j][row], row = t0-7+row
    __shared__ uint4 vlds[8 * 270];

    const int tid = threadIdx.x;
    const int bid = blockIdx.x;
    const int h  = bid & 7;
    const int b  = (bid >> 3) & 3;
    const int tb = bid >> 5;          // [0,16)
    const int t0 = tb * 256;

    #pragma unroll
    for (int i = 0; i < 9; i++) {
        int idx = i * 256 + tid;
        if (idx < 2160) {
            int row = idx % 270;
            int j   = idx / 270;
            int tt  = t0 - 7 + row;
            uint4 kc, vc;
            if ((unsigned)tt < (unsigned)T_) {
                const u16* g = qkv + ((size_t)b * T_ + tt) * NQKV + 512 + h * 64 + j * 8;
                kc = *(const uint4*)g;
                vc = *(const uint4*)(g + 512);
            } else {
                union { uint4 u; u16 s[8]; } pk, pv;
                #pragma unroll
                for (int e = 0; e < 8; e++) {
                    pk.s[e] = f2bf(bkv[h * 64 + j * 8 + e]);
                    pv.s[e] = f2bf(bkv[512 + h * 64 + j * 8 + e]);
                }
                kc = pk.u; vc = pv.u;
            }
            klds[j * 270 + row] = kc;
            vlds[j * 270 + row] = vc;
        }
    }
    __syncthreads();

    const size_t m = (size_t)b * T_ + t0 + tid;
    u16* qrow = qkv + m * NQKV + h * 64;

    float qf[64];
    #pragma unroll
    for (int j = 0; j < 8; j++) {
        union { uint4 u; u16 s[8]; } t;
        t.u = *(const uint4*)(qrow + j * 8);
        #pragma unroll
        for (int e = 0; e < 8; e++) qf[j * 8 + e] = bf2f(t.s[e]);
    }

    const float scale = 0.042313283f;   // ln(15)/64
    float s[WIN_];
    #pragma unroll
    for (int w = 0; w < WIN_; w++) {
        float acc = 0.f;
        #pragma unroll
        for (int j = 0; j < 8; j++) {
            union { uint4 u; u16 e[8]; } kc;
            kc.u = klds[j * 270 + tid + w];
            #pragma unroll
            for (int e2 = 0; e2 < 8; e2++)
                acc += qf[j * 8 + e2] * bf2f(kc.e[e2]);
        }
        s[w] = acc * scale;
    }

    float mx = s[0];
    #pragma unroll
    for (int w = 1; w < WIN_; w++) mx = fmaxf(mx, s[w]);
    float sum = 0.f;
    #pragma unroll
    for (int w = 0; w < WIN_; w++) { s[w] = __expf(s[w] - mx); sum += s[w]; }
    const float inv = 1.0f / sum;
    #pragma unroll
    for (int w = 0; w < WIN_; w++) s[w] *= inv;

    #pragma unroll
    for (int j = 0; j < 8; j++) {
        float o[8] = {};
        #pragma unroll
        for (int w = 0; w < WIN_; w++) {
            union { uint4 u; u16 e[8]; } vc;
            vc.u = vlds[j * 270 + tid + w];
            #pragma unroll
            for (int e2 = 0; e2 < 8; e2++) o[e2] += s[w] * bf2f(vc.e[e2]);
        }
        union { uint4 u; u16 e[8]; } oc;
        #pragma unroll
        for (int e2 = 0; e2 < 8; e2++) oc.e[e2] = f2bf(o[e2]);
        *(uint4*)(qrow + j * 8) = oc.u;
    }
}

// ---------------------------------------------------------------------------
// Workspace: 50 MiB total.
//   [0, 1.5Mi)    Wt_qkv (1536x512 bf16)
//   [1.5Mi, 2Mi)  Wpt    (512x512 bf16)
//   [2Mi, 50Mi)   qkv    (16384x1536 bf16); q section reused for attn output
// ---------------------------------------------------------------------------
extern "C" void kernel_launch(void* const* d_in, const int* in_sizes, int n_in,
                              void* d_out, int out_size, void* d_ws, size_t ws_size,
                              hipStream_t stream)
{
    const float* x    = (const float*)d_in[0];
    const float* mask = (const float*)d_in[1];
    const float* Wq   = (const float*)d_in[2];
    const float* bq   = (const float*)d_in[3];
    const float* Wkv  = (const float*)d_in[4];
    const float* bkv  = (const float*)d_in[5];
    const float* Wp   = (const float*)d_in[6];
    const float* bp   = (const float*)d_in[7];
    float* out = (float*)d_out;

    char* ws = (char*)d_ws;
    u16* Wt_qkv = (u16*)(ws);
    u16* Wpt    = (u16*)(ws + (size_t)(1536 * 1024));
    u16* qkv    = (u16*)(ws + (size_t)(2048 * 1024));

    pack_weights<<<NQKV * KDIM / 256, 256, 0, stream>>>(Wq, Wkv, Wp, Wt_qkv, Wpt);

    dim3 g1(M_ / 128, NQKV / 128);
    gemm_bt_128<true, false, false><<<g1, 256, 0, stream>>>(
        x, KDIM, mask, Wt_qkv, bq, bkv, qkv, KDIM, NQKV);

    attn_win2<<<(T_ / 256) * B_ * H_, 256, 0, stream>>>(qkv, bkv);

    dim3 g2(M_ / 128, C_ / 128);
    gemm_bt_128<false, true, true><<<g2, 256, 0, stream>>>(
        qkv, NQKV, mask, Wpt, bp, nullptr, out, KDIM, C_);
}